// Round 1
// baseline (139.958 us; speedup 1.0000x reference)
//
#include <hip/hip_runtime.h>
#include <hip/hip_cooperative_groups.h>
#include <math.h>

namespace cg = cooperative_groups;

#define N_NODES 32
#define DIM     128
#define NBLK    32
#define NTHR    256

struct GnnParams {
  const int* nt; const int* tr;
  const float* ne_w; const float* te_w; const float* ef_w;
  const float* w_ih; const float* w_hh; const float* b_ih; const float* b_hh;
  const float* ln_g; const float* ln_b;
  const float* fc1_w; const float* fc1_b;
  const float* ln2_g; const float* ln2_b;
  const float* fc2_w; const float* fc2_b;
  const int* hA; const int* hF;
  float* h_glob; float* out;
};

// ---------------- histogram over edges (index-only, loop-invariant) ---------
__global__ __launch_bounds__(NTHR) void hist_kernel(
    const int* __restrict__ es, const int* __restrict__ ed,
    const int* __restrict__ ef, int E,
    int* __restrict__ hA, int* __restrict__ hF)
{
  __shared__ int lA[N_NODES * N_NODES];
  __shared__ int lF[N_NODES * 6];
  const int t = threadIdx.x;
  for (int i = t; i < N_NODES * N_NODES; i += NTHR) lA[i] = 0;
  for (int i = t; i < N_NODES * 6;       i += NTHR) lF[i] = 0;
  __syncthreads();
  for (int e = blockIdx.x * NTHR + t; e < E; e += gridDim.x * NTHR) {
    int s = es[e], d = ed[e], f = ef[e];
    if ((unsigned)s < N_NODES && (unsigned)d < N_NODES) {
      atomicAdd(&lA[d * N_NODES + s], 1);
      atomicAdd(&lF[d * 6 + f], 1);
    }
  }
  __syncthreads();
  for (int i = t; i < N_NODES * N_NODES; i += NTHR) { int v = lA[i]; if (v) atomicAdd(&hA[i], v); }
  for (int i = t; i < N_NODES * 6;       i += NTHR) { int v = lF[i]; if (v) atomicAdd(&hF[i], v); }
}

// ---------------- cooperative GRU iteration kernel: one node per block ------
__global__ __launch_bounds__(NTHR) void gnn_kernel(GnnParams p)
{
  cg::grid_group grid = cg::this_grid();
  const int b = blockIdx.x;   // node id
  const int t = threadIdx.x;

  __shared__ float sh[N_NODES][DIM];   // all-node h (16 KB)
  __shared__ float sagg[DIM];
  __shared__ float sdots[6 * DIM];     // gi[384], gh[384]
  __shared__ float Arow[N_NODES];
  __shared__ float Bn[DIM];
  __shared__ float svals[DIM];
  __shared__ float pooled[2 * DIM];
  __shared__ float red[4];
  __shared__ float s_scalar[1];

  // ---- init: h0 row, A row, B row, cnt ----
  if (t < DIM) {
    float v = p.ne_w[p.nt[b] * DIM + t] + p.te_w[p.tr[b] * DIM + t];
    p.h_glob[b * DIM + t] = v;
  }
  if (t < N_NODES) Arow[t] = (float)p.hA[b * N_NODES + t];
  if (t < DIM) {
    float acc = 0.f;
#pragma unroll
    for (int f = 0; f < 6; ++f)
      acc = fmaf((float)p.hF[b * 6 + f], p.ef_w[f * DIM + t], acc);
    Bn[t] = acc;
  }
  __syncthreads();
  if (t == 0) {
    float c = 0.f;
    for (int s = 0; s < N_NODES; ++s) c += Arow[s];
    s_scalar[0] = 1.0f / fmaxf(c, 1.0f);
  }
  __syncthreads();
  const float inv_cnt = s_scalar[0];

  grid.sync();   // h0 of all nodes visible

  for (int it = 0; it < 5; ++it) {
    // load full h into LDS (coalesced float4)
    {
      const float4* src = (const float4*)p.h_glob;
      float4* dst = (float4*)(&sh[0][0]);
      for (int i = t; i < N_NODES * DIM / 4; i += NTHR) dst[i] = src[i];
    }
    __syncthreads();

    // agg row for this node: (A[b]·h + B[b]) / cnt[b]
    if (t < DIM) {
      float acc = Bn[t];
#pragma unroll 8
      for (int s = 0; s < N_NODES; ++s) acc = fmaf(Arow[s], sh[s][t], acc);
      sagg[t] = acc * inv_cnt;
    }
    __syncthreads();

    // 768 dot products of length 128: gi = agg @ w_ih^T, gh = h_b @ w_hh^T
#pragma unroll
    for (int rep = 0; rep < 3; ++rep) {
      const int d = t + rep * NTHR;
      const float* wrow = (d < 3 * DIM) ? (p.w_ih + d * DIM)
                                        : (p.w_hh + (d - 3 * DIM) * DIM);
      const float* xv = (d < 3 * DIM) ? sagg : &sh[b][0];
      const float4* w4 = (const float4*)wrow;
      const float4* x4 = (const float4*)xv;
      float acc = 0.f;
#pragma unroll
      for (int k = 0; k < DIM / 4; ++k) {
        float4 wv = w4[k]; float4 xq = x4[k];
        acc = fmaf(wv.x, xq.x, acc);
        acc = fmaf(wv.y, xq.y, acc);
        acc = fmaf(wv.z, xq.z, acc);
        acc = fmaf(wv.w, xq.w, acc);
      }
      sdots[d] = acc;
    }
    __syncthreads();

    // gates + pre-LN value
    if (t < DIM) {
      float ir  = sdots[t          ] + p.b_ih[t];
      float iz  = sdots[t +     DIM] + p.b_ih[t + DIM];
      float in_ = sdots[t + 2 * DIM] + p.b_ih[t + 2 * DIM];
      float hr  = sdots[3 * DIM + t          ] + p.b_hh[t];
      float hz  = sdots[3 * DIM + t +     DIM] + p.b_hh[t + DIM];
      float hn  = sdots[3 * DIM + t + 2 * DIM] + p.b_hh[t + 2 * DIM];
      float r  = 1.f / (1.f + expf(-(ir + hr)));
      float z  = 1.f / (1.f + expf(-(iz + hz)));
      float nn = tanhf(in_ + r * hn);
      svals[t] = (1.f - z) * nn + z * sh[b][t];
    }
    __syncthreads();

    // layernorm over 128 (two-pass, shuffle + LDS combine)
    if (t < DIM) {
      float s = svals[t];
#pragma unroll
      for (int o = 32; o > 0; o >>= 1) s += __shfl_down(s, o, 64);
      if ((t & 63) == 0) red[t >> 6] = s;
    }
    __syncthreads();
    const float mean = (red[0] + red[1]) * (1.0f / DIM);
    if (t < DIM) {
      float dx = svals[t] - mean;
      float s = dx * dx;
#pragma unroll
      for (int o = 32; o > 0; o >>= 1) s += __shfl_down(s, o, 64);
      if ((t & 63) == 0) red[2 + (t >> 6)] = s;
    }
    __syncthreads();
    const float var  = (red[2] + red[3]) * (1.0f / DIM);
    const float rstd = rsqrtf(var + 1e-5f);
    if (t < DIM) {
      float hnew = (svals[t] - mean) * rstd * p.ln_g[t] + p.ln_b[t];
      p.h_glob[b * DIM + t] = hnew;
    }
    grid.sync();   // all h rows updated + visible
  }

  // ---------------- head: pooling + fc1 + LN2 + relu + fc2 (block 0) -------
  if (b == 0) {
    const float4* src = (const float4*)p.h_glob;
    float4* dst = (float4*)(&sh[0][0]);
    for (int i = t; i < N_NODES * DIM / 4; i += NTHR) dst[i] = src[i];
    __syncthreads();

    if (t < DIM) {
      float s = 0.f, mx = -INFINITY;
#pragma unroll
      for (int n2 = 0; n2 < N_NODES; ++n2) {
        float v = sh[n2][t];
        s += v; mx = fmaxf(mx, v);
      }
      pooled[t]       = s * (1.0f / N_NODES);
      pooled[t + DIM] = mx;
    }
    __syncthreads();

    if (t < DIM) {
      const float4* w4 = (const float4*)(p.fc1_w + t * 2 * DIM);
      const float4* p4 = (const float4*)pooled;
      float acc = p.fc1_b[t];
#pragma unroll
      for (int k = 0; k < 2 * DIM / 4; ++k) {
        float4 wv = w4[k]; float4 pv = p4[k];
        acc = fmaf(wv.x, pv.x, acc);
        acc = fmaf(wv.y, pv.y, acc);
        acc = fmaf(wv.z, pv.z, acc);
        acc = fmaf(wv.w, pv.w, acc);
      }
      svals[t] = acc;
    }
    __syncthreads();

    if (t < DIM) {
      float s = svals[t];
#pragma unroll
      for (int o = 32; o > 0; o >>= 1) s += __shfl_down(s, o, 64);
      if ((t & 63) == 0) red[t >> 6] = s;
    }
    __syncthreads();
    const float mean2 = (red[0] + red[1]) * (1.0f / DIM);
    if (t < DIM) {
      float dx = svals[t] - mean2;
      float s = dx * dx;
#pragma unroll
      for (int o = 32; o > 0; o >>= 1) s += __shfl_down(s, o, 64);
      if ((t & 63) == 0) red[2 + (t >> 6)] = s;
    }
    __syncthreads();
    const float var2  = (red[2] + red[3]) * (1.0f / DIM);
    const float rstd2 = rsqrtf(var2 + 1e-5f);
    __syncthreads();   // ensure all mean2 reads done before red[0..1] reuse
    if (t < DIM) {
      float x = (svals[t] - mean2) * rstd2 * p.ln2_g[t] + p.ln2_b[t];
      x = fmaxf(x, 0.f);
      float s = x * p.fc2_w[t];
#pragma unroll
      for (int o = 32; o > 0; o >>= 1) s += __shfl_down(s, o, 64);
      if ((t & 63) == 0) red[t >> 6] = s;
    }
    __syncthreads();
    if (t == 0) p.out[0] = red[0] + red[1] + p.fc2_b[0];
  }
}

// ---------------------------------------------------------------------------
extern "C" void kernel_launch(void* const* d_in, const int* in_sizes, int n_in,
                              void* d_out, int out_size, void* d_ws, size_t ws_size,
                              hipStream_t stream)
{
  const int*   nt    = (const int*)d_in[0];
  const int*   tr    = (const int*)d_in[1];
  const int*   es    = (const int*)d_in[2];
  const int*   ed    = (const int*)d_in[3];
  const int*   ef    = (const int*)d_in[4];
  const float* ne_w  = (const float*)d_in[5];
  const float* te_w  = (const float*)d_in[6];
  const float* ef_w  = (const float*)d_in[7];
  const float* w_ih  = (const float*)d_in[8];
  const float* w_hh  = (const float*)d_in[9];
  const float* b_ih  = (const float*)d_in[10];
  const float* b_hh  = (const float*)d_in[11];
  const float* ln_g  = (const float*)d_in[12];
  const float* ln_b  = (const float*)d_in[13];
  const float* fc1_w = (const float*)d_in[14];
  const float* fc1_b = (const float*)d_in[15];
  const float* ln2_g = (const float*)d_in[16];
  const float* ln2_b = (const float*)d_in[17];
  const float* fc2_w = (const float*)d_in[18];
  const float* fc2_b = (const float*)d_in[19];

  const int E = in_sizes[2];

  int*   hA     = (int*)d_ws;                         // 1024 ints
  int*   hF     = (int*)((char*)d_ws + 4096);         // 192 ints
  float* h_glob = (float*)((char*)d_ws + 8192);       // 4096 floats

  hipMemsetAsync(d_ws, 0, 4864, stream);

  hipLaunchKernelGGL(hist_kernel, dim3(256), dim3(NTHR), 0, stream,
                     es, ed, ef, E, hA, hF);

  GnnParams prm;
  prm.nt = nt; prm.tr = tr;
  prm.ne_w = ne_w; prm.te_w = te_w; prm.ef_w = ef_w;
  prm.w_ih = w_ih; prm.w_hh = w_hh; prm.b_ih = b_ih; prm.b_hh = b_hh;
  prm.ln_g = ln_g; prm.ln_b = ln_b;
  prm.fc1_w = fc1_w; prm.fc1_b = fc1_b;
  prm.ln2_g = ln2_g; prm.ln2_b = ln2_b;
  prm.fc2_w = fc2_w; prm.fc2_b = fc2_b;
  prm.hA = hA; prm.hF = hF;
  prm.h_glob = h_glob; prm.out = (float*)d_out;

  void* args[] = { &prm };
  hipLaunchCooperativeKernel((const void*)gnn_kernel, dim3(NBLK), dim3(NTHR),
                             args, 0, stream);
}

// Round 2
// 124.659 us; speedup vs baseline: 1.1227x; 1.1227x over previous
//
#include <hip/hip_runtime.h>
#include <math.h>

#define N_NODES 32
#define DIM     128
#define NBLK    32
#define NTHR_H  256
#define NTHR_G  768   // 12 waves: one dot-row per thread (768 = 2*3*DIM)

struct GnnParams {
  const int* nt; const int* tr;
  const float* ne_w; const float* te_w; const float* ef_w;
  const float* w_ih; const float* w_hh; const float* b_ih; const float* b_hh;
  const float* ln_g; const float* ln_b;
  const float* fc1_w; const float* fc1_b;
  const float* ln2_g; const float* ln2_b;
  const float* fc2_w; const float* fc2_b;
  const int* hA; const int* hF;
  int* bar;              // [0]=count [1]=generation (memset to 0 per launch)
  float* h0; float* h1;  // ping-pong h buffers [N_NODES*DIM]
  float* out;
};

// ---------------- lightweight grid barrier (replaces cg grid.sync) ----------
__device__ __forceinline__ void grid_barrier(int* bar) {
  __syncthreads();
  if (threadIdx.x == 0) {
    int gen = __hip_atomic_load(&bar[1], __ATOMIC_RELAXED, __HIP_MEMORY_SCOPE_AGENT);
    __threadfence();   // release: flush this CU/XCD's dirty lines device-wide
    int arrived = __hip_atomic_fetch_add(&bar[0], 1, __ATOMIC_RELAXED,
                                         __HIP_MEMORY_SCOPE_AGENT);
    if (arrived == NBLK - 1) {
      __hip_atomic_store(&bar[0], 0, __ATOMIC_RELAXED, __HIP_MEMORY_SCOPE_AGENT);
      __hip_atomic_fetch_add(&bar[1], 1, __ATOMIC_RELEASE, __HIP_MEMORY_SCOPE_AGENT);
    } else {
      while (__hip_atomic_load(&bar[1], __ATOMIC_RELAXED,
                               __HIP_MEMORY_SCOPE_AGENT) == gen)
        __builtin_amdgcn_s_sleep(1);   // 64-cycle naps, not ockl's coarse backoff
    }
    __threadfence();   // acquire: invalidate so fresh h is visible
  }
  __syncthreads();
}

// ---------------- histogram over edges (index-only, loop-invariant) ---------
__global__ __launch_bounds__(NTHR_H) void hist_kernel(
    const int* __restrict__ es, const int* __restrict__ ed,
    const int* __restrict__ ef, int E,
    int* __restrict__ hA, int* __restrict__ hF)
{
  __shared__ int lA[N_NODES * N_NODES];
  __shared__ int lF[N_NODES * 6];
  const int t = threadIdx.x;
  for (int i = t; i < N_NODES * N_NODES; i += NTHR_H) lA[i] = 0;
  for (int i = t; i < N_NODES * 6;       i += NTHR_H) lF[i] = 0;
  __syncthreads();

  const int E4 = E >> 2;
  const int4* es4 = (const int4*)es;
  const int4* ed4 = (const int4*)ed;
  const int4* ef4 = (const int4*)ef;
  for (int i = blockIdx.x * NTHR_H + t; i < E4; i += gridDim.x * NTHR_H) {
    int4 s4 = es4[i], d4 = ed4[i], f4 = ef4[i];
    #define DO_EDGE(S, D, F) \
      if ((unsigned)(S) < N_NODES && (unsigned)(D) < N_NODES) { \
        atomicAdd(&lA[(D) * N_NODES + (S)], 1); \
        atomicAdd(&lF[(D) * 6 + (F)], 1); }
    DO_EDGE(s4.x, d4.x, f4.x)
    DO_EDGE(s4.y, d4.y, f4.y)
    DO_EDGE(s4.z, d4.z, f4.z)
    DO_EDGE(s4.w, d4.w, f4.w)
  }
  // tail (E % 4)
  if (blockIdx.x == 0) {
    for (int e = (E4 << 2) + t; e < E; e += NTHR_H) {
      int s = es[e], d = ed[e], f = ef[e];
      DO_EDGE(s, d, f)
    }
  }
  #undef DO_EDGE
  __syncthreads();
  for (int i = t; i < N_NODES * N_NODES; i += NTHR_H) { int v = lA[i]; if (v) atomicAdd(&hA[i], v); }
  for (int i = t; i < N_NODES * 6;       i += NTHR_H) { int v = lF[i]; if (v) atomicAdd(&hF[i], v); }
}

// ---------------- GRU iteration kernel: one node per block, 768 threads -----
__global__ __launch_bounds__(NTHR_G) void gnn_kernel(GnnParams p)
{
  const int b = blockIdx.x;   // node id
  const int t = threadIdx.x;

  __shared__ float sh[N_NODES][DIM];   // all-node h (16 KB)
  __shared__ float sagg[DIM];
  __shared__ float sdots[6 * DIM];
  __shared__ float Arow[N_NODES];
  __shared__ float Bn[DIM];
  __shared__ float svals[DIM];
  __shared__ float pooled[2 * DIM];
  __shared__ float red[4];
  __shared__ float s_scalar[1];

  // ---- init: A row, B row, cnt; h0 for ALL nodes computed locally ----------
  if (t < N_NODES) Arow[t] = (float)p.hA[b * N_NODES + t];
  if (t >= 64 && t < 64 + DIM) {
    const int d0 = t - 64;
    float acc = 0.f;
#pragma unroll
    for (int f = 0; f < 6; ++f)
      acc = fmaf((float)p.hF[b * 6 + f], p.ef_w[f * DIM + d0], acc);
    Bn[d0] = acc;
  }
  for (int i = t; i < N_NODES * DIM; i += NTHR_G) {
    const int s = i >> 7, d0 = i & (DIM - 1);
    sh[s][d0] = p.ne_w[p.nt[s] * DIM + d0] + p.te_w[p.tr[s] * DIM + d0];
  }
  __syncthreads();
  if (t == 0) {
    float c = 0.f;
    for (int s = 0; s < N_NODES; ++s) c += Arow[s];
    s_scalar[0] = 1.0f / fmaxf(c, 1.0f);
  }
  __syncthreads();
  const float inv_cnt = s_scalar[0];

  float* hbuf[2] = { p.h0, p.h1 };

  for (int it = 0; it < 5; ++it) {
    // agg row for this node: (A[b]·h + B[b]) / cnt[b]
    if (t < DIM) {
      float acc = Bn[t];
#pragma unroll 8
      for (int s = 0; s < N_NODES; ++s) acc = fmaf(Arow[s], sh[s][t], acc);
      sagg[t] = acc * inv_cnt;
    }
    __syncthreads();

    // 768 dots of length 128: one row per thread
    {
      const float* wrow = (t < 3 * DIM) ? (p.w_ih + t * DIM)
                                        : (p.w_hh + (t - 3 * DIM) * DIM);
      const float* xv   = (t < 3 * DIM) ? sagg : &sh[b][0];
      const float4* w4 = (const float4*)wrow;
      const float4* x4 = (const float4*)xv;
      float acc = 0.f;
#pragma unroll 8
      for (int k = 0; k < DIM / 4; ++k) {
        float4 wv = w4[k]; float4 xq = x4[k];
        acc = fmaf(wv.x, xq.x, acc);
        acc = fmaf(wv.y, xq.y, acc);
        acc = fmaf(wv.z, xq.z, acc);
        acc = fmaf(wv.w, xq.w, acc);
      }
      sdots[t] = acc;
    }
    __syncthreads();

    // gates + pre-LN value
    if (t < DIM) {
      float ir  = sdots[t          ] + p.b_ih[t];
      float iz  = sdots[t +     DIM] + p.b_ih[t + DIM];
      float in_ = sdots[t + 2 * DIM] + p.b_ih[t + 2 * DIM];
      float hr  = sdots[3 * DIM + t          ] + p.b_hh[t];
      float hz  = sdots[3 * DIM + t +     DIM] + p.b_hh[t + DIM];
      float hn  = sdots[3 * DIM + t + 2 * DIM] + p.b_hh[t + 2 * DIM];
      float r  = 1.f / (1.f + expf(-(ir + hr)));
      float z  = 1.f / (1.f + expf(-(iz + hz)));
      float nn = tanhf(in_ + r * hn);
      svals[t] = (1.f - z) * nn + z * sh[b][t];
    }
    __syncthreads();

    // layernorm over 128 (t<128 = exactly 2 waves)
    if (t < DIM) {
      float s = svals[t];
#pragma unroll
      for (int o = 32; o > 0; o >>= 1) s += __shfl_down(s, o, 64);
      if ((t & 63) == 0) red[t >> 6] = s;
    }
    __syncthreads();
    const float mean = (red[0] + red[1]) * (1.0f / DIM);
    if (t < DIM) {
      float dx = svals[t] - mean;
      float s = dx * dx;
#pragma unroll
      for (int o = 32; o > 0; o >>= 1) s += __shfl_down(s, o, 64);
      if ((t & 63) == 0) red[2 + (t >> 6)] = s;
    }
    __syncthreads();
    const float var  = (red[2] + red[3]) * (1.0f / DIM);
    const float rstd = rsqrtf(var + 1e-5f);
    if (t < DIM) {
      float hnew = (svals[t] - mean) * rstd * p.ln_g[t] + p.ln_b[t];
      hbuf[it & 1][b * DIM + t] = hnew;   // ping-pong: race-free w/ 1 barrier
    }

    grid_barrier(p.bar);

    // refresh the all-node h snapshot (skip for exiting blocks on last iter)
    if (it < 4 || b == 0) {
      const float4* src = (const float4*)hbuf[it & 1];
      float4* dst = (float4*)(&sh[0][0]);
      for (int i = t; i < N_NODES * DIM / 4; i += NTHR_G) dst[i] = src[i];
    }
    __syncthreads();
  }

  // ---------------- head: pooling + fc1 + LN2 + relu + fc2 (block 0) --------
  if (b == 0) {
    if (t < DIM) {
      float s = 0.f, mx = -INFINITY;
#pragma unroll
      for (int n2 = 0; n2 < N_NODES; ++n2) {
        float v = sh[n2][t];
        s += v; mx = fmaxf(mx, v);
      }
      pooled[t]       = s * (1.0f / N_NODES);
      pooled[t + DIM] = mx;
    }
    __syncthreads();

    if (t < DIM) {
      const float4* w4 = (const float4*)(p.fc1_w + t * 2 * DIM);
      const float4* p4 = (const float4*)pooled;
      float acc = p.fc1_b[t];
#pragma unroll 8
      for (int k = 0; k < 2 * DIM / 4; ++k) {
        float4 wv = w4[k]; float4 pv = p4[k];
        acc = fmaf(wv.x, pv.x, acc);
        acc = fmaf(wv.y, pv.y, acc);
        acc = fmaf(wv.z, pv.z, acc);
        acc = fmaf(wv.w, pv.w, acc);
      }
      svals[t] = acc;
    }
    __syncthreads();

    if (t < DIM) {
      float s = svals[t];
#pragma unroll
      for (int o = 32; o > 0; o >>= 1) s += __shfl_down(s, o, 64);
      if ((t & 63) == 0) red[t >> 6] = s;
    }
    __syncthreads();
    const float mean2 = (red[0] + red[1]) * (1.0f / DIM);
    if (t < DIM) {
      float dx = svals[t] - mean2;
      float s = dx * dx;
#pragma unroll
      for (int o = 32; o > 0; o >>= 1) s += __shfl_down(s, o, 64);
      if ((t & 63) == 0) red[2 + (t >> 6)] = s;
    }
    __syncthreads();
    const float var2  = (red[2] + red[3]) * (1.0f / DIM);
    const float rstd2 = rsqrtf(var2 + 1e-5f);
    __syncthreads();
    if (t < DIM) {
      float x = (svals[t] - mean2) * rstd2 * p.ln2_g[t] + p.ln2_b[t];
      x = fmaxf(x, 0.f);
      float s = x * p.fc2_w[t];
#pragma unroll
      for (int o = 32; o > 0; o >>= 1) s += __shfl_down(s, o, 64);
      if ((t & 63) == 0) red[t >> 6] = s;
    }
    __syncthreads();
    if (t == 0) p.out[0] = red[0] + red[1] + p.fc2_b[0];
  }
}

// ---------------------------------------------------------------------------
extern "C" void kernel_launch(void* const* d_in, const int* in_sizes, int n_in,
                              void* d_out, int out_size, void* d_ws, size_t ws_size,
                              hipStream_t stream)
{
  const int*   nt    = (const int*)d_in[0];
  const int*   tr    = (const int*)d_in[1];
  const int*   es    = (const int*)d_in[2];
  const int*   ed    = (const int*)d_in[3];
  const int*   ef    = (const int*)d_in[4];
  const float* ne_w  = (const float*)d_in[5];
  const float* te_w  = (const float*)d_in[6];
  const float* ef_w  = (const float*)d_in[7];
  const float* w_ih  = (const float*)d_in[8];
  const float* w_hh  = (const float*)d_in[9];
  const float* b_ih  = (const float*)d_in[10];
  const float* b_hh  = (const float*)d_in[11];
  const float* ln_g  = (const float*)d_in[12];
  const float* ln_b  = (const float*)d_in[13];
  const float* fc1_w = (const float*)d_in[14];
  const float* fc1_b = (const float*)d_in[15];
  const float* ln2_g = (const float*)d_in[16];
  const float* ln2_b = (const float*)d_in[17];
  const float* fc2_w = (const float*)d_in[18];
  const float* fc2_b = (const float*)d_in[19];

  const int E = in_sizes[2];

  // ws layout: hA[1024]@0 | hF[192]@4096 | bar[2]@4992 | h0@8192 | h1@24576
  int*   hA  = (int*)d_ws;
  int*   hF  = (int*)((char*)d_ws + 4096);
  int*   bar = (int*)((char*)d_ws + 4992);
  float* h0  = (float*)((char*)d_ws + 8192);
  float* h1  = (float*)((char*)d_ws + 24576);

  hipMemsetAsync(d_ws, 0, 5120, stream);   // zero hA, hF, barrier state

  hipLaunchKernelGGL(hist_kernel, dim3(128), dim3(NTHR_H), 0, stream,
                     es, ed, ef, E, hA, hF);

  GnnParams prm;
  prm.nt = nt; prm.tr = tr;
  prm.ne_w = ne_w; prm.te_w = te_w; prm.ef_w = ef_w;
  prm.w_ih = w_ih; prm.w_hh = w_hh; prm.b_ih = b_ih; prm.b_hh = b_hh;
  prm.ln_g = ln_g; prm.ln_b = ln_b;
  prm.fc1_w = fc1_w; prm.fc1_b = fc1_b;
  prm.ln2_g = ln2_g; prm.ln2_b = ln2_b;
  prm.fc2_w = fc2_w; prm.fc2_b = fc2_b;
  prm.hA = hA; prm.hF = hF; prm.bar = bar;
  prm.h0 = h0; prm.h1 = h1;
  prm.out = (float*)d_out;

  void* args[] = { &prm };
  hipLaunchCooperativeKernel((const void*)gnn_kernel, dim3(NBLK), dim3(NTHR_G),
                             args, 0, stream);
}

// Round 3
// 124.141 us; speedup vs baseline: 1.1274x; 1.0042x over previous
//
#include <hip/hip_runtime.h>
#include <math.h>

#define N_NODES 32
#define DIM     128
#define NBLK    32
#define NTHR_H  256
#define NTHR_G  768   // 12 waves: one dot-row per thread (768 = 2*3*DIM)

struct GnnParams {
  const int* nt; const int* tr;
  const float* ne_w; const float* te_w; const float* ef_w;
  const float* w_ih; const float* w_hh; const float* b_ih; const float* b_hh;
  const float* ln_g; const float* ln_b;
  const float* fc1_w; const float* fc1_b;
  const float* ln2_g; const float* ln2_b;
  const float* fc2_w; const float* fc2_b;
  const int* hA; const int* hF;
  int* bar;              // [0]=count [1]=generation (memset to 0 per launch)
  float* h0; float* h1;  // ping-pong h buffers [N_NODES*DIM]
  float* out;
};

// ---------------- lightweight grid barrier (replaces cg grid.sync) ----------
__device__ __forceinline__ void grid_barrier(int* bar) {
  __syncthreads();
  if (threadIdx.x == 0) {
    int gen = __hip_atomic_load(&bar[1], __ATOMIC_RELAXED, __HIP_MEMORY_SCOPE_AGENT);
    __threadfence();   // release: flush this CU/XCD's dirty lines device-wide
    int arrived = __hip_atomic_fetch_add(&bar[0], 1, __ATOMIC_RELAXED,
                                         __HIP_MEMORY_SCOPE_AGENT);
    if (arrived == NBLK - 1) {
      __hip_atomic_store(&bar[0], 0, __ATOMIC_RELAXED, __HIP_MEMORY_SCOPE_AGENT);
      __hip_atomic_fetch_add(&bar[1], 1, __ATOMIC_RELEASE, __HIP_MEMORY_SCOPE_AGENT);
    } else {
      while (__hip_atomic_load(&bar[1], __ATOMIC_RELAXED,
                               __HIP_MEMORY_SCOPE_AGENT) == gen)
        __builtin_amdgcn_s_sleep(1);   // 64-cycle naps, not ockl's coarse backoff
    }
    __threadfence();   // acquire: invalidate so fresh h is visible
  }
  __syncthreads();
}

// ---------------- histogram over edges (index-only, loop-invariant) ---------
__global__ __launch_bounds__(NTHR_H) void hist_kernel(
    const int* __restrict__ es, const int* __restrict__ ed,
    const int* __restrict__ ef, int E,
    int* __restrict__ hA, int* __restrict__ hF)
{
  __shared__ int lA[N_NODES * N_NODES];
  __shared__ int lF[N_NODES * 6];
  const int t = threadIdx.x;
  for (int i = t; i < N_NODES * N_NODES; i += NTHR_H) lA[i] = 0;
  for (int i = t; i < N_NODES * 6;       i += NTHR_H) lF[i] = 0;
  __syncthreads();

  const int E4 = E >> 2;
  const int4* es4 = (const int4*)es;
  const int4* ed4 = (const int4*)ed;
  const int4* ef4 = (const int4*)ef;
  for (int i = blockIdx.x * NTHR_H + t; i < E4; i += gridDim.x * NTHR_H) {
    int4 s4 = es4[i], d4 = ed4[i], f4 = ef4[i];
    #define DO_EDGE(S, D, F) \
      if ((unsigned)(S) < N_NODES && (unsigned)(D) < N_NODES) { \
        atomicAdd(&lA[(D) * N_NODES + (S)], 1); \
        atomicAdd(&lF[(D) * 6 + (F)], 1); }
    DO_EDGE(s4.x, d4.x, f4.x)
    DO_EDGE(s4.y, d4.y, f4.y)
    DO_EDGE(s4.z, d4.z, f4.z)
    DO_EDGE(s4.w, d4.w, f4.w)
  }
  // tail (E % 4)
  if (blockIdx.x == 0) {
    for (int e = (E4 << 2) + t; e < E; e += NTHR_H) {
      int s = es[e], d = ed[e], f = ef[e];
      DO_EDGE(s, d, f)
    }
  }
  #undef DO_EDGE
  __syncthreads();
  for (int i = t; i < N_NODES * N_NODES; i += NTHR_H) { int v = lA[i]; if (v) atomicAdd(&hA[i], v); }
  for (int i = t; i < N_NODES * 6;       i += NTHR_H) { int v = lF[i]; if (v) atomicAdd(&hF[i], v); }
}

// ---------------- GRU iteration kernel: one node per block, 768 threads -----
__global__ __launch_bounds__(NTHR_G) void gnn_kernel(GnnParams p)
{
  const int b = blockIdx.x;   // node id
  const int t = threadIdx.x;

  __shared__ float sh[N_NODES][DIM];   // all-node h (16 KB)
  __shared__ float sagg[DIM];
  __shared__ float sdots[6 * DIM];
  __shared__ float Arow[N_NODES];
  __shared__ float Bn[DIM];
  __shared__ float svals[DIM];
  __shared__ float pooled[2 * DIM];
  __shared__ float red[4];
  __shared__ float s_scalar[1];

  // ---- init: A row, B row, cnt; h0 for ALL nodes computed locally ----------
  if (t < N_NODES) Arow[t] = (float)p.hA[b * N_NODES + t];
  if (t >= 64 && t < 64 + DIM) {
    const int d0 = t - 64;
    float acc = 0.f;
#pragma unroll
    for (int f = 0; f < 6; ++f)
      acc = fmaf((float)p.hF[b * 6 + f], p.ef_w[f * DIM + d0], acc);
    Bn[d0] = acc;
  }
  for (int i = t; i < N_NODES * DIM; i += NTHR_G) {
    const int s = i >> 7, d0 = i & (DIM - 1);
    sh[s][d0] = p.ne_w[p.nt[s] * DIM + d0] + p.te_w[p.tr[s] * DIM + d0];
  }
  __syncthreads();
  if (t == 0) {
    float c = 0.f;
    for (int s = 0; s < N_NODES; ++s) c += Arow[s];
    s_scalar[0] = 1.0f / fmaxf(c, 1.0f);
  }
  __syncthreads();
  const float inv_cnt = s_scalar[0];

  float* hbuf[2] = { p.h0, p.h1 };

  for (int it = 0; it < 5; ++it) {
    // agg row for this node: (A[b]·h + B[b]) / cnt[b]
    if (t < DIM) {
      float acc = Bn[t];
#pragma unroll 8
      for (int s = 0; s < N_NODES; ++s) acc = fmaf(Arow[s], sh[s][t], acc);
      sagg[t] = acc * inv_cnt;
    }
    __syncthreads();

    // 768 dots of length 128: one row per thread
    {
      const float* wrow = (t < 3 * DIM) ? (p.w_ih + t * DIM)
                                        : (p.w_hh + (t - 3 * DIM) * DIM);
      const float* xv   = (t < 3 * DIM) ? sagg : &sh[b][0];
      const float4* w4 = (const float4*)wrow;
      const float4* x4 = (const float4*)xv;
      float acc = 0.f;
#pragma unroll 8
      for (int k = 0; k < DIM / 4; ++k) {
        float4 wv = w4[k]; float4 xq = x4[k];
        acc = fmaf(wv.x, xq.x, acc);
        acc = fmaf(wv.y, xq.y, acc);
        acc = fmaf(wv.z, xq.z, acc);
        acc = fmaf(wv.w, xq.w, acc);
      }
      sdots[t] = acc;
    }
    __syncthreads();

    // gates + pre-LN value
    if (t < DIM) {
      float ir  = sdots[t          ] + p.b_ih[t];
      float iz  = sdots[t +     DIM] + p.b_ih[t + DIM];
      float in_ = sdots[t + 2 * DIM] + p.b_ih[t + 2 * DIM];
      float hr  = sdots[3 * DIM + t          ] + p.b_hh[t];
      float hz  = sdots[3 * DIM + t +     DIM] + p.b_hh[t + DIM];
      float hn  = sdots[3 * DIM + t + 2 * DIM] + p.b_hh[t + 2 * DIM];
      float r  = 1.f / (1.f + expf(-(ir + hr)));
      float z  = 1.f / (1.f + expf(-(iz + hz)));
      float nn = tanhf(in_ + r * hn);
      svals[t] = (1.f - z) * nn + z * sh[b][t];
    }
    __syncthreads();

    // layernorm over 128 (t<128 = exactly 2 waves)
    if (t < DIM) {
      float s = svals[t];
#pragma unroll
      for (int o = 32; o > 0; o >>= 1) s += __shfl_down(s, o, 64);
      if ((t & 63) == 0) red[t >> 6] = s;
    }
    __syncthreads();
    const float mean = (red[0] + red[1]) * (1.0f / DIM);
    if (t < DIM) {
      float dx = svals[t] - mean;
      float s = dx * dx;
#pragma unroll
      for (int o = 32; o > 0; o >>= 1) s += __shfl_down(s, o, 64);
      if ((t & 63) == 0) red[2 + (t >> 6)] = s;
    }
    __syncthreads();
    const float var  = (red[2] + red[3]) * (1.0f / DIM);
    const float rstd = rsqrtf(var + 1e-5f);
    if (t < DIM) {
      float hnew = (svals[t] - mean) * rstd * p.ln_g[t] + p.ln_b[t];
      hbuf[it & 1][b * DIM + t] = hnew;   // ping-pong: race-free w/ 1 barrier
    }

    grid_barrier(p.bar);

    // refresh the all-node h snapshot (skip for exiting blocks on last iter)
    if (it < 4 || b == 0) {
      const float4* src = (const float4*)hbuf[it & 1];
      float4* dst = (float4*)(&sh[0][0]);
      for (int i = t; i < N_NODES * DIM / 4; i += NTHR_G) dst[i] = src[i];
    }
    __syncthreads();
  }

  // ---------------- head: pooling + fc1 + LN2 + relu + fc2 (block 0) --------
  if (b == 0) {
    if (t < DIM) {
      float s = 0.f, mx = -INFINITY;
#pragma unroll
      for (int n2 = 0; n2 < N_NODES; ++n2) {
        float v = sh[n2][t];
        s += v; mx = fmaxf(mx, v);
      }
      pooled[t]       = s * (1.0f / N_NODES);
      pooled[t + DIM] = mx;
    }
    __syncthreads();

    if (t < DIM) {
      const float4* w4 = (const float4*)(p.fc1_w + t * 2 * DIM);
      const float4* p4 = (const float4*)pooled;
      float acc = p.fc1_b[t];
#pragma unroll 8
      for (int k = 0; k < 2 * DIM / 4; ++k) {
        float4 wv = w4[k]; float4 pv = p4[k];
        acc = fmaf(wv.x, pv.x, acc);
        acc = fmaf(wv.y, pv.y, acc);
        acc = fmaf(wv.z, pv.z, acc);
        acc = fmaf(wv.w, pv.w, acc);
      }
      svals[t] = acc;
    }
    __syncthreads();

    if (t < DIM) {
      float s = svals[t];
#pragma unroll
      for (int o = 32; o > 0; o >>= 1) s += __shfl_down(s, o, 64);
      if ((t & 63) == 0) red[t >> 6] = s;
    }
    __syncthreads();
    const float mean2 = (red[0] + red[1]) * (1.0f / DIM);
    if (t < DIM) {
      float dx = svals[t] - mean2;
      float s = dx * dx;
#pragma unroll
      for (int o = 32; o > 0; o >>= 1) s += __shfl_down(s, o, 64);
      if ((t & 63) == 0) red[2 + (t >> 6)] = s;
    }
    __syncthreads();
    const float var2  = (red[2] + red[3]) * (1.0f / DIM);
    const float rstd2 = rsqrtf(var2 + 1e-5f);
    __syncthreads();
    if (t < DIM) {
      float x = (svals[t] - mean2) * rstd2 * p.ln2_g[t] + p.ln2_b[t];
      x = fmaxf(x, 0.f);
      float s = x * p.fc2_w[t];
#pragma unroll
      for (int o = 32; o > 0; o >>= 1) s += __shfl_down(s, o, 64);
      if ((t & 63) == 0) red[t >> 6] = s;
    }
    __syncthreads();
    if (t == 0) p.out[0] = red[0] + red[1] + p.fc2_b[0];
  }
}

// ---------------------------------------------------------------------------
extern "C" void kernel_launch(void* const* d_in, const int* in_sizes, int n_in,
                              void* d_out, int out_size, void* d_ws, size_t ws_size,
                              hipStream_t stream)
{
  const int*   nt    = (const int*)d_in[0];
  const int*   tr    = (const int*)d_in[1];
  const int*   es    = (const int*)d_in[2];
  const int*   ed    = (const int*)d_in[3];
  const int*   ef    = (const int*)d_in[4];
  const float* ne_w  = (const float*)d_in[5];
  const float* te_w  = (const float*)d_in[6];
  const float* ef_w  = (const float*)d_in[7];
  const float* w_ih  = (const float*)d_in[8];
  const float* w_hh  = (const float*)d_in[9];
  const float* b_ih  = (const float*)d_in[10];
  const float* b_hh  = (const float*)d_in[11];
  const float* ln_g  = (const float*)d_in[12];
  const float* ln_b  = (const float*)d_in[13];
  const float* fc1_w = (const float*)d_in[14];
  const float* fc1_b = (const float*)d_in[15];
  const float* ln2_g = (const float*)d_in[16];
  const float* ln2_b = (const float*)d_in[17];
  const float* fc2_w = (const float*)d_in[18];
  const float* fc2_b = (const float*)d_in[19];

  const int E = in_sizes[2];

  // ws layout: hA[1024]@0 | hF[192]@4096 | bar[2]@4992 | h0@8192 | h1@24576
  int*   hA  = (int*)d_ws;
  int*   hF  = (int*)((char*)d_ws + 4096);
  int*   bar = (int*)((char*)d_ws + 4992);
  float* h0  = (float*)((char*)d_ws + 8192);
  float* h1  = (float*)((char*)d_ws + 24576);

  hipMemsetAsync(d_ws, 0, 5120, stream);   // zero hA, hF, barrier state

  hipLaunchKernelGGL(hist_kernel, dim3(128), dim3(NTHR_H), 0, stream,
                     es, ed, ef, E, hA, hF);

  GnnParams prm;
  prm.nt = nt; prm.tr = tr;
  prm.ne_w = ne_w; prm.te_w = te_w; prm.ef_w = ef_w;
  prm.w_ih = w_ih; prm.w_hh = w_hh; prm.b_ih = b_ih; prm.b_hh = b_hh;
  prm.ln_g = ln_g; prm.ln_b = ln_b;
  prm.fc1_w = fc1_w; prm.fc1_b = fc1_b;
  prm.ln2_g = ln2_g; prm.ln2_b = ln2_b;
  prm.fc2_w = fc2_w; prm.fc2_b = fc2_b;
  prm.hA = hA; prm.hF = hF; prm.bar = bar;
  prm.h0 = h0; prm.h1 = h1;
  prm.out = (float*)d_out;

  void* args[] = { &prm };
  hipLaunchCooperativeKernel((const void*)gnn_kernel, dim3(NBLK), dim3(NTHR_G),
                             args, 0, stream);
}

// Round 4
// 121.981 us; speedup vs baseline: 1.1474x; 1.0177x over previous
//
#include <hip/hip_runtime.h>
#include <math.h>

#define N_NODES 32
#define DIM     128
#define NBLK    32
#define NTHR_H  256
#define NTHR_G  768   // 12 waves: one dot-row per thread (768 = 2*3*DIM)

struct GnnParams {
  const int* nt; const int* tr;
  const float* ne_w; const float* te_w; const float* ef_w;
  const float* w_ih; const float* w_hh; const float* b_ih; const float* b_hh;
  const float* ln_g; const float* ln_b;
  const float* fc1_w; const float* fc1_b;
  const float* ln2_g; const float* ln2_b;
  const float* fc2_w; const float* fc2_b;
  const int* hA; const int* hF;
  int* bar;              // [0]=count [1]=generation (memset to 0 per launch)
  float* h0; float* h1;  // ping-pong h buffers [N_NODES*DIM]
  float* out;
};

// ---------------- lightweight grid barrier (replaces cg grid.sync) ----------
__device__ __forceinline__ void grid_barrier(int* bar) {
  __syncthreads();
  if (threadIdx.x == 0) {
    int gen = __hip_atomic_load(&bar[1], __ATOMIC_RELAXED, __HIP_MEMORY_SCOPE_AGENT);
    __threadfence();   // release: flush this CU/XCD's dirty lines device-wide
    int arrived = __hip_atomic_fetch_add(&bar[0], 1, __ATOMIC_RELAXED,
                                         __HIP_MEMORY_SCOPE_AGENT);
    if (arrived == NBLK - 1) {
      __hip_atomic_store(&bar[0], 0, __ATOMIC_RELAXED, __HIP_MEMORY_SCOPE_AGENT);
      __hip_atomic_fetch_add(&bar[1], 1, __ATOMIC_RELEASE, __HIP_MEMORY_SCOPE_AGENT);
    } else {
      while (__hip_atomic_load(&bar[1], __ATOMIC_RELAXED,
                               __HIP_MEMORY_SCOPE_AGENT) == gen)
        __builtin_amdgcn_s_sleep(1);   // 64-cycle naps, not ockl's coarse backoff
    }
    __threadfence();   // acquire: invalidate so fresh h is visible
  }
  __syncthreads();
}

// ---------------- histogram over edges (index-only, loop-invariant) ---------
__global__ __launch_bounds__(NTHR_H) void hist_kernel(
    const int* __restrict__ es, const int* __restrict__ ed,
    const int* __restrict__ ef, int E,
    int* __restrict__ hA, int* __restrict__ hF)
{
  __shared__ int lA[N_NODES * N_NODES];
  __shared__ int lF[N_NODES * 6];
  const int t = threadIdx.x;
  for (int i = t; i < N_NODES * N_NODES; i += NTHR_H) lA[i] = 0;
  for (int i = t; i < N_NODES * 6;       i += NTHR_H) lF[i] = 0;
  __syncthreads();

  const int E4 = E >> 2;
  const int4* es4 = (const int4*)es;
  const int4* ed4 = (const int4*)ed;
  const int4* ef4 = (const int4*)ef;
  for (int i = blockIdx.x * NTHR_H + t; i < E4; i += gridDim.x * NTHR_H) {
    int4 s4 = es4[i], d4 = ed4[i], f4 = ef4[i];
    #define DO_EDGE(S, D, F) \
      if ((unsigned)(S) < N_NODES && (unsigned)(D) < N_NODES) { \
        atomicAdd(&lA[(D) * N_NODES + (S)], 1); \
        atomicAdd(&lF[(D) * 6 + (F)], 1); }
    DO_EDGE(s4.x, d4.x, f4.x)
    DO_EDGE(s4.y, d4.y, f4.y)
    DO_EDGE(s4.z, d4.z, f4.z)
    DO_EDGE(s4.w, d4.w, f4.w)
  }
  // tail (E % 4)
  if (blockIdx.x == 0) {
    for (int e = (E4 << 2) + t; e < E; e += NTHR_H) {
      int s = es[e], d = ed[e], f = ef[e];
      DO_EDGE(s, d, f)
    }
  }
  #undef DO_EDGE
  __syncthreads();
  for (int i = t; i < N_NODES * N_NODES; i += NTHR_H) { int v = lA[i]; if (v) atomicAdd(&hA[i], v); }
  for (int i = t; i < N_NODES * 6;       i += NTHR_H) { int v = lF[i]; if (v) atomicAdd(&hF[i], v); }
}

// ---------------- GRU iteration kernel: one node per block, 768 threads -----
__global__ __launch_bounds__(NTHR_G) void gnn_kernel(GnnParams p)
{
  const int b = blockIdx.x;   // node id
  const int t = threadIdx.x;

  __shared__ float sh[N_NODES][DIM];   // all-node h (16 KB)
  __shared__ float sagg[DIM];
  __shared__ float sdots[6 * DIM];
  __shared__ float Arow[N_NODES];
  __shared__ float Bn[DIM];
  __shared__ float svals[DIM];
  __shared__ float pooled[2 * DIM];
  __shared__ float red[4];
  __shared__ float s_scalar[1];

  // ---- init: A row, B row, cnt; h0 for ALL nodes computed locally ----------
  if (t < N_NODES) Arow[t] = (float)p.hA[b * N_NODES + t];
  if (t >= 64 && t < 64 + DIM) {
    const int d0 = t - 64;
    float acc = 0.f;
#pragma unroll
    for (int f = 0; f < 6; ++f)
      acc = fmaf((float)p.hF[b * 6 + f], p.ef_w[f * DIM + d0], acc);
    Bn[d0] = acc;
  }
  for (int i = t; i < N_NODES * DIM; i += NTHR_G) {
    const int s = i >> 7, d0 = i & (DIM - 1);
    sh[s][d0] = p.ne_w[p.nt[s] * DIM + d0] + p.te_w[p.tr[s] * DIM + d0];
  }
  __syncthreads();
  if (t == 0) {
    float c = 0.f;
    for (int s = 0; s < N_NODES; ++s) c += Arow[s];
    s_scalar[0] = 1.0f / fmaxf(c, 1.0f);
  }
  __syncthreads();
  const float inv_cnt = s_scalar[0];

  float* hbuf[2] = { p.h0, p.h1 };

  for (int it = 0; it < 5; ++it) {
    // agg row for this node: (A[b]·h + B[b]) / cnt[b]
    if (t < DIM) {
      float acc = Bn[t];
#pragma unroll 8
      for (int s = 0; s < N_NODES; ++s) acc = fmaf(Arow[s], sh[s][t], acc);
      sagg[t] = acc * inv_cnt;
    }
    __syncthreads();

    // 768 dots of length 128: one row per thread
    {
      const float* wrow = (t < 3 * DIM) ? (p.w_ih + t * DIM)
                                        : (p.w_hh + (t - 3 * DIM) * DIM);
      const float* xv   = (t < 3 * DIM) ? sagg : &sh[b][0];
      const float4* w4 = (const float4*)wrow;
      const float4* x4 = (const float4*)xv;
      float acc = 0.f;
#pragma unroll 8
      for (int k = 0; k < DIM / 4; ++k) {
        float4 wv = w4[k]; float4 xq = x4[k];
        acc = fmaf(wv.x, xq.x, acc);
        acc = fmaf(wv.y, xq.y, acc);
        acc = fmaf(wv.z, xq.z, acc);
        acc = fmaf(wv.w, xq.w, acc);
      }
      sdots[t] = acc;
    }
    __syncthreads();

    // gates + pre-LN value
    if (t < DIM) {
      float ir  = sdots[t          ] + p.b_ih[t];
      float iz  = sdots[t +     DIM] + p.b_ih[t + DIM];
      float in_ = sdots[t + 2 * DIM] + p.b_ih[t + 2 * DIM];
      float hr  = sdots[3 * DIM + t          ] + p.b_hh[t];
      float hz  = sdots[3 * DIM + t +     DIM] + p.b_hh[t + DIM];
      float hn  = sdots[3 * DIM + t + 2 * DIM] + p.b_hh[t + 2 * DIM];
      float r  = 1.f / (1.f + expf(-(ir + hr)));
      float z  = 1.f / (1.f + expf(-(iz + hz)));
      float nn = tanhf(in_ + r * hn);
      svals[t] = (1.f - z) * nn + z * sh[b][t];
    }
    __syncthreads();

    // layernorm over 128 (t<128 = exactly 2 waves)
    if (t < DIM) {
      float s = svals[t];
#pragma unroll
      for (int o = 32; o > 0; o >>= 1) s += __shfl_down(s, o, 64);
      if ((t & 63) == 0) red[t >> 6] = s;
    }
    __syncthreads();
    const float mean = (red[0] + red[1]) * (1.0f / DIM);
    if (t < DIM) {
      float dx = svals[t] - mean;
      float s = dx * dx;
#pragma unroll
      for (int o = 32; o > 0; o >>= 1) s += __shfl_down(s, o, 64);
      if ((t & 63) == 0) red[2 + (t >> 6)] = s;
    }
    __syncthreads();
    const float var  = (red[2] + red[3]) * (1.0f / DIM);
    const float rstd = rsqrtf(var + 1e-5f);
    if (t < DIM) {
      float hnew = (svals[t] - mean) * rstd * p.ln_g[t] + p.ln_b[t];
      hbuf[it & 1][b * DIM + t] = hnew;   // ping-pong: race-free w/ 1 barrier
    }

    grid_barrier(p.bar);

    // refresh the all-node h snapshot (skip for exiting blocks on last iter)
    if (it < 4 || b == 0) {
      const float4* src = (const float4*)hbuf[it & 1];
      float4* dst = (float4*)(&sh[0][0]);
      for (int i = t; i < N_NODES * DIM / 4; i += NTHR_G) dst[i] = src[i];
    }
    __syncthreads();
  }

  // ---------------- head: pooling + fc1 + LN2 + relu + fc2 (block 0) --------
  if (b == 0) {
    if (t < DIM) {
      float s = 0.f, mx = -INFINITY;
#pragma unroll
      for (int n2 = 0; n2 < N_NODES; ++n2) {
        float v = sh[n2][t];
        s += v; mx = fmaxf(mx, v);
      }
      pooled[t]       = s * (1.0f / N_NODES);
      pooled[t + DIM] = mx;
    }
    __syncthreads();

    if (t < DIM) {
      const float4* w4 = (const float4*)(p.fc1_w + t * 2 * DIM);
      const float4* p4 = (const float4*)pooled;
      float acc = p.fc1_b[t];
#pragma unroll 8
      for (int k = 0; k < 2 * DIM / 4; ++k) {
        float4 wv = w4[k]; float4 pv = p4[k];
        acc = fmaf(wv.x, pv.x, acc);
        acc = fmaf(wv.y, pv.y, acc);
        acc = fmaf(wv.z, pv.z, acc);
        acc = fmaf(wv.w, pv.w, acc);
      }
      svals[t] = acc;
    }
    __syncthreads();

    if (t < DIM) {
      float s = svals[t];
#pragma unroll
      for (int o = 32; o > 0; o >>= 1) s += __shfl_down(s, o, 64);
      if ((t & 63) == 0) red[t >> 6] = s;
    }
    __syncthreads();
    const float mean2 = (red[0] + red[1]) * (1.0f / DIM);
    if (t < DIM) {
      float dx = svals[t] - mean2;
      float s = dx * dx;
#pragma unroll
      for (int o = 32; o > 0; o >>= 1) s += __shfl_down(s, o, 64);
      if ((t & 63) == 0) red[2 + (t >> 6)] = s;
    }
    __syncthreads();
    const float var2  = (red[2] + red[3]) * (1.0f / DIM);
    const float rstd2 = rsqrtf(var2 + 1e-5f);
    __syncthreads();
    if (t < DIM) {
      float x = (svals[t] - mean2) * rstd2 * p.ln2_g[t] + p.ln2_b[t];
      x = fmaxf(x, 0.f);
      float s = x * p.fc2_w[t];
#pragma unroll
      for (int o = 32; o > 0; o >>= 1) s += __shfl_down(s, o, 64);
      if ((t & 63) == 0) red[t >> 6] = s;
    }
    __syncthreads();
    if (t == 0) p.out[0] = red[0] + red[1] + p.fc2_b[0];
  }
}

// ---------------------------------------------------------------------------
extern "C" void kernel_launch(void* const* d_in, const int* in_sizes, int n_in,
                              void* d_out, int out_size, void* d_ws, size_t ws_size,
                              hipStream_t stream)
{
  const int*   nt    = (const int*)d_in[0];
  const int*   tr    = (const int*)d_in[1];
  const int*   es    = (const int*)d_in[2];
  const int*   ed    = (const int*)d_in[3];
  const int*   ef    = (const int*)d_in[4];
  const float* ne_w  = (const float*)d_in[5];
  const float* te_w  = (const float*)d_in[6];
  const float* ef_w  = (const float*)d_in[7];
  const float* w_ih  = (const float*)d_in[8];
  const float* w_hh  = (const float*)d_in[9];
  const float* b_ih  = (const float*)d_in[10];
  const float* b_hh  = (const float*)d_in[11];
  const float* ln_g  = (const float*)d_in[12];
  const float* ln_b  = (const float*)d_in[13];
  const float* fc1_w = (const float*)d_in[14];
  const float* fc1_b = (const float*)d_in[15];
  const float* ln2_g = (const float*)d_in[16];
  const float* ln2_b = (const float*)d_in[17];
  const float* fc2_w = (const float*)d_in[18];
  const float* fc2_b = (const float*)d_in[19];

  const int E = in_sizes[2];

  // ws layout: hA[1024]@0 | hF[192]@4096 | bar[2]@4992 | h0@8192 | h1@24576
  int*   hA  = (int*)d_ws;
  int*   hF  = (int*)((char*)d_ws + 4096);
  int*   bar = (int*)((char*)d_ws + 4992);
  float* h0  = (float*)((char*)d_ws + 8192);
  float* h1  = (float*)((char*)d_ws + 24576);

  hipMemsetAsync(d_ws, 0, 5120, stream);   // zero hA, hF, barrier state

  hipLaunchKernelGGL(hist_kernel, dim3(128), dim3(NTHR_H), 0, stream,
                     es, ed, ef, E, hA, hF);

  GnnParams prm;
  prm.nt = nt; prm.tr = tr;
  prm.ne_w = ne_w; prm.te_w = te_w; prm.ef_w = ef_w;
  prm.w_ih = w_ih; prm.w_hh = w_hh; prm.b_ih = b_ih; prm.b_hh = b_hh;
  prm.ln_g = ln_g; prm.ln_b = ln_b;
  prm.fc1_w = fc1_w; prm.fc1_b = fc1_b;
  prm.ln2_g = ln2_g; prm.ln2_b = ln2_b;
  prm.fc2_w = fc2_w; prm.fc2_b = fc2_b;
  prm.hA = hA; prm.hF = hF; prm.bar = bar;
  prm.h0 = h0; prm.h1 = h1;
  prm.out = (float*)d_out;

  void* args[] = { &prm };
  hipLaunchCooperativeKernel((const void*)gnn_kernel, dim3(NBLK), dim3(NTHR_G),
                             args, 0, stream);
}

// Round 5
// 120.777 us; speedup vs baseline: 1.1588x; 1.0100x over previous
//
#include <hip/hip_runtime.h>
#include <math.h>

#define N_NODES 32
#define DIM     128
#define NBLK    32
#define NTHR_H  256
#define NTHR_G  768   // 12 waves: one dot-row per thread (768 = 2*3*DIM)

struct GnnParams {
  const int* nt; const int* tr;
  const float* ne_w; const float* te_w; const float* ef_w;
  const float* w_ih; const float* w_hh; const float* b_ih; const float* b_hh;
  const float* ln_g; const float* ln_b;
  const float* fc1_w; const float* fc1_b;
  const float* ln2_g; const float* ln2_b;
  const float* fc2_w; const float* fc2_b;
  const int* hA; const int* hF;
  int* bar;              // [0]=count [1]=generation (memset to 0 per launch)
  float* h0; float* h1;  // ping-pong h buffers [N_NODES*DIM]
  float* out;
};

// ---------------- lightweight grid barrier (replaces cg grid.sync) ----------
__device__ __forceinline__ void grid_barrier(int* bar) {
  __syncthreads();
  if (threadIdx.x == 0) {
    int gen = __hip_atomic_load(&bar[1], __ATOMIC_RELAXED, __HIP_MEMORY_SCOPE_AGENT);
    __threadfence();   // release: flush this CU/XCD's dirty lines device-wide
    int arrived = __hip_atomic_fetch_add(&bar[0], 1, __ATOMIC_RELAXED,
                                         __HIP_MEMORY_SCOPE_AGENT);
    if (arrived == NBLK - 1) {
      __hip_atomic_store(&bar[0], 0, __ATOMIC_RELAXED, __HIP_MEMORY_SCOPE_AGENT);
      __hip_atomic_fetch_add(&bar[1], 1, __ATOMIC_RELEASE, __HIP_MEMORY_SCOPE_AGENT);
    } else {
      while (__hip_atomic_load(&bar[1], __ATOMIC_RELAXED,
                               __HIP_MEMORY_SCOPE_AGENT) == gen)
        __builtin_amdgcn_s_sleep(1);   // 64-cycle naps, not ockl's coarse backoff
    }
    __threadfence();   // acquire: invalidate so fresh h is visible
  }
  __syncthreads();
}

// ---------------- histogram over edges (index-only, loop-invariant) ---------
__global__ __launch_bounds__(NTHR_H) void hist_kernel(
    const int* __restrict__ es, const int* __restrict__ ed,
    const int* __restrict__ ef, int E,
    int* __restrict__ hA, int* __restrict__ hF)
{
  __shared__ int lA[N_NODES * N_NODES];
  __shared__ int lF[N_NODES * 6];
  const int t = threadIdx.x;
  for (int i = t; i < N_NODES * N_NODES; i += NTHR_H) lA[i] = 0;
  for (int i = t; i < N_NODES * 6;       i += NTHR_H) lF[i] = 0;
  __syncthreads();

  const int E4 = E >> 2;
  const int4* es4 = (const int4*)es;
  const int4* ed4 = (const int4*)ed;
  const int4* ef4 = (const int4*)ef;
  for (int i = blockIdx.x * NTHR_H + t; i < E4; i += gridDim.x * NTHR_H) {
    int4 s4 = es4[i], d4 = ed4[i], f4 = ef4[i];
    #define DO_EDGE(S, D, F) \
      if ((unsigned)(S) < N_NODES && (unsigned)(D) < N_NODES) { \
        atomicAdd(&lA[(D) * N_NODES + (S)], 1); \
        atomicAdd(&lF[(D) * 6 + (F)], 1); }
    DO_EDGE(s4.x, d4.x, f4.x)
    DO_EDGE(s4.y, d4.y, f4.y)
    DO_EDGE(s4.z, d4.z, f4.z)
    DO_EDGE(s4.w, d4.w, f4.w)
  }
  // tail (E % 4)
  if (blockIdx.x == 0) {
    for (int e = (E4 << 2) + t; e < E; e += NTHR_H) {
      int s = es[e], d = ed[e], f = ef[e];
      DO_EDGE(s, d, f)
    }
  }
  #undef DO_EDGE
  __syncthreads();
  for (int i = t; i < N_NODES * N_NODES; i += NTHR_H) { int v = lA[i]; if (v) atomicAdd(&hA[i], v); }
  for (int i = t; i < N_NODES * 6;       i += NTHR_H) { int v = lF[i]; if (v) atomicAdd(&hF[i], v); }
}

// ---------------- GRU iteration kernel: one node per block, 768 threads -----
__global__ __launch_bounds__(NTHR_G) void gnn_kernel(GnnParams p)
{
  const int b = blockIdx.x;   // node id
  const int t = threadIdx.x;

  __shared__ float sh[N_NODES][DIM];   // all-node h (16 KB)
  __shared__ float sagg[DIM];
  __shared__ float sdots[6 * DIM];
  __shared__ float Arow[N_NODES];
  __shared__ float Bn[DIM];
  __shared__ float svals[DIM];
  __shared__ float pooled[2 * DIM];
  __shared__ float red[4];
  __shared__ float s_scalar[1];

  // ---- init: A row, B row, cnt; h0 for ALL nodes computed locally ----------
  if (t < N_NODES) Arow[t] = (float)p.hA[b * N_NODES + t];
  if (t >= 64 && t < 64 + DIM) {
    const int d0 = t - 64;
    float acc = 0.f;
#pragma unroll
    for (int f = 0; f < 6; ++f)
      acc = fmaf((float)p.hF[b * 6 + f], p.ef_w[f * DIM + d0], acc);
    Bn[d0] = acc;
  }
  for (int i = t; i < N_NODES * DIM; i += NTHR_G) {
    const int s = i >> 7, d0 = i & (DIM - 1);
    sh[s][d0] = p.ne_w[p.nt[s] * DIM + d0] + p.te_w[p.tr[s] * DIM + d0];
  }
  __syncthreads();
  if (t == 0) {
    float c = 0.f;
    for (int s = 0; s < N_NODES; ++s) c += Arow[s];
    s_scalar[0] = 1.0f / fmaxf(c, 1.0f);
  }
  __syncthreads();
  const float inv_cnt = s_scalar[0];

  float* hbuf[2] = { p.h0, p.h1 };

  for (int it = 0; it < 5; ++it) {
    // agg row for this node: (A[b]·h + B[b]) / cnt[b]
    if (t < DIM) {
      float acc = Bn[t];
#pragma unroll 8
      for (int s = 0; s < N_NODES; ++s) acc = fmaf(Arow[s], sh[s][t], acc);
      sagg[t] = acc * inv_cnt;
    }
    __syncthreads();

    // 768 dots of length 128: one row per thread
    {
      const float* wrow = (t < 3 * DIM) ? (p.w_ih + t * DIM)
                                        : (p.w_hh + (t - 3 * DIM) * DIM);
      const float* xv   = (t < 3 * DIM) ? sagg : &sh[b][0];
      const float4* w4 = (const float4*)wrow;
      const float4* x4 = (const float4*)xv;
      float acc = 0.f;
#pragma unroll 8
      for (int k = 0; k < DIM / 4; ++k) {
        float4 wv = w4[k]; float4 xq = x4[k];
        acc = fmaf(wv.x, xq.x, acc);
        acc = fmaf(wv.y, xq.y, acc);
        acc = fmaf(wv.z, xq.z, acc);
        acc = fmaf(wv.w, xq.w, acc);
      }
      sdots[t] = acc;
    }
    __syncthreads();

    // gates + pre-LN value
    if (t < DIM) {
      float ir  = sdots[t          ] + p.b_ih[t];
      float iz  = sdots[t +     DIM] + p.b_ih[t + DIM];
      float in_ = sdots[t + 2 * DIM] + p.b_ih[t + 2 * DIM];
      float hr  = sdots[3 * DIM + t          ] + p.b_hh[t];
      float hz  = sdots[3 * DIM + t +     DIM] + p.b_hh[t + DIM];
      float hn  = sdots[3 * DIM + t + 2 * DIM] + p.b_hh[t + 2 * DIM];
      float r  = 1.f / (1.f + expf(-(ir + hr)));
      float z  = 1.f / (1.f + expf(-(iz + hz)));
      float nn = tanhf(in_ + r * hn);
      svals[t] = (1.f - z) * nn + z * sh[b][t];
    }
    __syncthreads();

    // layernorm over 128 (t<128 = exactly 2 waves)
    if (t < DIM) {
      float s = svals[t];
#pragma unroll
      for (int o = 32; o > 0; o >>= 1) s += __shfl_down(s, o, 64);
      if ((t & 63) == 0) red[t >> 6] = s;
    }
    __syncthreads();
    const float mean = (red[0] + red[1]) * (1.0f / DIM);
    if (t < DIM) {
      float dx = svals[t] - mean;
      float s = dx * dx;
#pragma unroll
      for (int o = 32; o > 0; o >>= 1) s += __shfl_down(s, o, 64);
      if ((t & 63) == 0) red[2 + (t >> 6)] = s;
    }
    __syncthreads();
    const float var  = (red[2] + red[3]) * (1.0f / DIM);
    const float rstd = rsqrtf(var + 1e-5f);
    if (t < DIM) {
      float hnew = (svals[t] - mean) * rstd * p.ln_g[t] + p.ln_b[t];
      hbuf[it & 1][b * DIM + t] = hnew;   // ping-pong: race-free w/ 1 barrier
    }

    grid_barrier(p.bar);

    // refresh the all-node h snapshot (skip for exiting blocks on last iter)
    if (it < 4 || b == 0) {
      const float4* src = (const float4*)hbuf[it & 1];
      float4* dst = (float4*)(&sh[0][0]);
      for (int i = t; i < N_NODES * DIM / 4; i += NTHR_G) dst[i] = src[i];
    }
    __syncthreads();
  }

  // ---------------- head: pooling + fc1 + LN2 + relu + fc2 (block 0) --------
  if (b == 0) {
    if (t < DIM) {
      float s = 0.f, mx = -INFINITY;
#pragma unroll
      for (int n2 = 0; n2 < N_NODES; ++n2) {
        float v = sh[n2][t];
        s += v; mx = fmaxf(mx, v);
      }
      pooled[t]       = s * (1.0f / N_NODES);
      pooled[t + DIM] = mx;
    }
    __syncthreads();

    if (t < DIM) {
      const float4* w4 = (const float4*)(p.fc1_w + t * 2 * DIM);
      const float4* p4 = (const float4*)pooled;
      float acc = p.fc1_b[t];
#pragma unroll 8
      for (int k = 0; k < 2 * DIM / 4; ++k) {
        float4 wv = w4[k]; float4 pv = p4[k];
        acc = fmaf(wv.x, pv.x, acc);
        acc = fmaf(wv.y, pv.y, acc);
        acc = fmaf(wv.z, pv.z, acc);
        acc = fmaf(wv.w, pv.w, acc);
      }
      svals[t] = acc;
    }
    __syncthreads();

    if (t < DIM) {
      float s = svals[t];
#pragma unroll
      for (int o = 32; o > 0; o >>= 1) s += __shfl_down(s, o, 64);
      if ((t & 63) == 0) red[t >> 6] = s;
    }
    __syncthreads();
    const float mean2 = (red[0] + red[1]) * (1.0f / DIM);
    if (t < DIM) {
      float dx = svals[t] - mean2;
      float s = dx * dx;
#pragma unroll
      for (int o = 32; o > 0; o >>= 1) s += __shfl_down(s, o, 64);
      if ((t & 63) == 0) red[2 + (t >> 6)] = s;
    }
    __syncthreads();
    const float var2  = (red[2] + red[3]) * (1.0f / DIM);
    const float rstd2 = rsqrtf(var2 + 1e-5f);
    __syncthreads();
    if (t < DIM) {
      float x = (svals[t] - mean2) * rstd2 * p.ln2_g[t] + p.ln2_b[t];
      x = fmaxf(x, 0.f);
      float s = x * p.fc2_w[t];
#pragma unroll
      for (int o = 32; o > 0; o >>= 1) s += __shfl_down(s, o, 64);
      if ((t & 63) == 0) red[t >> 6] = s;
    }
    __syncthreads();
    if (t == 0) p.out[0] = red[0] + red[1] + p.fc2_b[0];
  }
}

// ---------------------------------------------------------------------------
extern "C" void kernel_launch(void* const* d_in, const int* in_sizes, int n_in,
                              void* d_out, int out_size, void* d_ws, size_t ws_size,
                              hipStream_t stream)
{
  const int*   nt    = (const int*)d_in[0];
  const int*   tr    = (const int*)d_in[1];
  const int*   es    = (const int*)d_in[2];
  const int*   ed    = (const int*)d_in[3];
  const int*   ef    = (const int*)d_in[4];
  const float* ne_w  = (const float*)d_in[5];
  const float* te_w  = (const float*)d_in[6];
  const float* ef_w  = (const float*)d_in[7];
  const float* w_ih  = (const float*)d_in[8];
  const float* w_hh  = (const float*)d_in[9];
  const float* b_ih  = (const float*)d_in[10];
  const float* b_hh  = (const float*)d_in[11];
  const float* ln_g  = (const float*)d_in[12];
  const float* ln_b  = (const float*)d_in[13];
  const float* fc1_w = (const float*)d_in[14];
  const float* fc1_b = (const float*)d_in[15];
  const float* ln2_g = (const float*)d_in[16];
  const float* ln2_b = (const float*)d_in[17];
  const float* fc2_w = (const float*)d_in[18];
  const float* fc2_b = (const float*)d_in[19];

  const int E = in_sizes[2];

  // ws layout: hA[1024]@0 | hF[192]@4096 | bar[2]@4992 | h0@8192 | h1@24576
  int*   hA  = (int*)d_ws;
  int*   hF  = (int*)((char*)d_ws + 4096);
  int*   bar = (int*)((char*)d_ws + 4992);
  float* h0  = (float*)((char*)d_ws + 8192);
  float* h1  = (float*)((char*)d_ws + 24576);

  hipMemsetAsync(d_ws, 0, 5120, stream);   // zero hA, hF, barrier state

  hipLaunchKernelGGL(hist_kernel, dim3(128), dim3(NTHR_H), 0, stream,
                     es, ed, ef, E, hA, hF);

  GnnParams prm;
  prm.nt = nt; prm.tr = tr;
  prm.ne_w = ne_w; prm.te_w = te_w; prm.ef_w = ef_w;
  prm.w_ih = w_ih; prm.w_hh = w_hh; prm.b_ih = b_ih; prm.b_hh = b_hh;
  prm.ln_g = ln_g; prm.ln_b = ln_b;
  prm.fc1_w = fc1_w; prm.fc1_b = fc1_b;
  prm.ln2_g = ln2_g; prm.ln2_b = ln2_b;
  prm.fc2_w = fc2_w; prm.fc2_b = fc2_b;
  prm.hA = hA; prm.hF = hF; prm.bar = bar;
  prm.h0 = h0; prm.h1 = h1;
  prm.out = (float*)d_out;

  void* args[] = { &prm };
  hipLaunchCooperativeKernel((const void*)gnn_kernel, dim3(NBLK), dim3(NTHR_G),
                             args, 0, stream);
}